// Round 8
// baseline (155.759 us; speedup 1.0000x reference)
//
#include <hip/hip_runtime.h>
#include <math.h>

#define BSZ 4096
#define NTOT 8192
#define DIM 128
#define NCHUNK 32          // 256-col chunks

typedef __attribute__((ext_vector_type(8))) short short8;   // 8 bf16 = 4 VGPR
typedef __attribute__((ext_vector_type(4))) float float4v;  // MFMA acc

constexpr float INV_T = 1.0f / 0.07f;
constexpr float M0    = INV_T;                 // row max of logits = diag = 1/T
constexpr float LOG2E = 1.4426950408889634f;
constexpr float K1    = INV_T * LOG2E;         // e^(s-M0) = 2^(c*K1 - K1)
constexpr float C3    = -0.5f * LOG2E;         // a = e^(-l^2/2) = 2^(l^2*C3)

__device__ __forceinline__ unsigned short f2bf(float x) {
    union { float f; unsigned u; } u; u.f = x;
    return (unsigned short)((u.u + 0x7FFFu + ((u.u >> 16) & 1)) >> 16);
}
__device__ __forceinline__ float bf2f(unsigned short s) {
    union { unsigned u; float f; } u; u.u = ((unsigned)s) << 16;
    return u.f;
}
__device__ __forceinline__ unsigned pack2(float a, float b) {
    return (unsigned)f2bf(a) | ((unsigned)f2bf(b) << 16);
}

// ---------- kernel A: fp32 normalize -> bf16 F[i][d]; also zeroes out[0] ----------
__global__ __launch_bounds__(256) void norm_k(const float* __restrict__ feat,
                                              unsigned short* __restrict__ F,
                                              float* __restrict__ out) {
    if (blockIdx.x == 0 && threadIdx.x == 0) out[0] = 0.f;
    const int tid = threadIdx.x;
    const int wv = tid >> 6, l = tid & 63;
    const int g = l >> 3, j = l & 7;
    const int row = blockIdx.x * 32 + wv * 8 + g;
    const int b = row & (BSZ - 1), v = row >> 12;
    const float4* src = reinterpret_cast<const float4*>(feat + (size_t)(b * 2 + v) * DIM) + j * 4;
    const float4 x0 = src[0], x1 = src[1], x2 = src[2], x3 = src[3];
    float s = x0.x*x0.x + x0.y*x0.y + x0.z*x0.z + x0.w*x0.w
            + x1.x*x1.x + x1.y*x1.y + x1.z*x1.z + x1.w*x1.w
            + x2.x*x2.x + x2.y*x2.y + x2.z*x2.z + x2.w*x2.w
            + x3.x*x3.x + x3.y*x3.y + x3.z*x3.z + x3.w*x3.w;
    s += __shfl_xor(s, 1); s += __shfl_xor(s, 2); s += __shfl_xor(s, 4);
    const float inv = 1.0f / sqrtf(s + 1e-12f);
    uint4 w0, w1;
    w0.x = pack2(x0.x*inv, x0.y*inv); w0.y = pack2(x0.z*inv, x0.w*inv);
    w0.z = pack2(x1.x*inv, x1.y*inv); w0.w = pack2(x1.z*inv, x1.w*inv);
    w1.x = pack2(x2.x*inv, x2.y*inv); w1.y = pack2(x2.z*inv, x2.w*inv);
    w1.z = pack2(x3.x*inv, x3.y*inv); w1.w = pack2(x3.z*inv, x3.w*inv);
    uint4* dst = reinterpret_cast<uint4*>(F + (size_t)row * DIM);
    dst[j * 2]     = w0;
    dst[j * 2 + 1] = w1;
}

// ---------- kernel B: per-block partials of h/svec (no atomics) ----------
// 256 blocks x 128 thr, 32 k's each. h_p[b][10][128], sv_p[b][16].
__global__ __launch_bounds__(128) void hsum_p(const unsigned short* __restrict__ F,
                                              const float* __restrict__ labels,
                                              float* __restrict__ h_p, float* __restrict__ sv_p) {
    const int t = threadIdx.x;             // d = 0..127
    const int k0 = blockIdx.x * 32;
    float acc[10];
#pragma unroll
    for (int m = 0; m < 10; ++m) acc[m] = 0.f;
    float sv = 0.f;
    for (int kk = 0; kk < 32; ++kk) {
        const int k = k0 + kk;
        const float li = labels[k & (BSZ - 1)];
        const float a = __builtin_amdgcn_exp2f(li * li * C3);
        const float f = bf2f(F[(size_t)k * DIM + t]);
        float pm = a;
#pragma unroll
        for (int m = 0; m < 10; ++m) {
            acc[m] = fmaf(pm, f, acc[m]);
            if (t == m) sv += pm;
            pm *= li;
        }
    }
    float* hp = h_p + (size_t)blockIdx.x * (10 * DIM);
#pragma unroll
    for (int m = 0; m < 10; ++m) hp[m * DIM + t] = acc[m];
    if (t < 10) sv_p[blockIdx.x * 16 + t] = sv;
}

// ---------- kernel B2: fold 256 partials -> h[10][128], svec[10] ----------
__global__ void hreduce(const float* __restrict__ h_p, const float* __restrict__ sv_p,
                        float* __restrict__ h, float* __restrict__ svec) {
    const int m = blockIdx.x;      // 0..9
    const int t = threadIdx.x;     // 0..127
    float s = 0.f;
    for (int b = 0; b < 256; ++b) s += h_p[(size_t)b * (10 * DIM) + m * DIM + t];
    h[m * DIM + t] = s;
    if (m == 0 && t < 10) {
        float v = 0.f;
        for (int b = 0; b < 256; ++b) v += sv_p[b * 16 + t];
        svec[t] = v;
    }
}

// ---------- kernel C: MFMA pairwise sweep, den only, B double-buffer prefetch ----------
// 64-row stripes, wave owns 64 rows x 256 cols. grid 1024 x 256thr.
__global__ __launch_bounds__(256, 4) void supcon_mfma(
    const unsigned short* __restrict__ F, float* __restrict__ den_p)
{
    const int tid    = threadIdx.x;
    const int wv     = tid >> 6;
    const int l      = tid & 63;
    const int stripe = blockIdx.x >> 3;        // 0..127
    const int quad   = blockIdx.x & 7;         // 0..7
    const int chunk  = quad * 4 + wv;          // 0..31
    const int row0   = stripe * 64;
    const int colbeg = chunk * 256;
    const int l15 = l & 15, lh = l >> 4;

    // A fragments: row = row0 + set*16 + (l&15), k = kc*32 + (l>>4)*8 + j  (validated r3)
    short8 a[4][4];
#pragma unroll
    for (int set = 0; set < 4; ++set) {
        const unsigned short* rp = F + (size_t)(row0 + set * 16 + l15) * DIM + lh * 8;
#pragma unroll
        for (int kc = 0; kc < 4; ++kc)
            a[set][kc] = *reinterpret_cast<const short8*>(rp + kc * 32);
    }

    float den[16];
#pragma unroll
    for (int p = 0; p < 16; ++p) den[p] = 0.f;

#define LOADB(cb, dst)                                                              \
    {                                                                               \
        const int c0 = (colbeg + (cb) * 16) & (NTOT - 1);                           \
        const unsigned short* cp = F + (size_t)(c0 + l15) * DIM + lh * 8;           \
        dst[0] = *reinterpret_cast<const short8*>(cp);                              \
        dst[1] = *reinterpret_cast<const short8*>(cp + 32);                         \
        dst[2] = *reinterpret_cast<const short8*>(cp + 64);                         \
        dst[3] = *reinterpret_cast<const short8*>(cp + 96);                         \
    }

#define COMPUTE(buf, cb)                                                            \
    {                                                                               \
        const int col0 = colbeg + (cb) * 16;                                        \
        _Pragma("unroll")                                                           \
        for (int set = 0; set < 4; ++set) {                                         \
            float4v acc = {0.f, 0.f, 0.f, 0.f};                                     \
            _Pragma("unroll")                                                       \
            for (int kc = 0; kc < 4; ++kc)                                          \
                acc = __builtin_amdgcn_mfma_f32_16x16x32_bf16(a[set][kc], buf[kc],  \
                                                              acc, 0, 0, 0);       \
            const bool dtile = (col0 == row0 + set * 16);                           \
            _Pragma("unroll")                                                       \
            for (int r = 0; r < 4; ++r) {                                           \
                float e = __builtin_amdgcn_exp2f(__builtin_fmaf(acc[r], K1, -K1));  \
                if (dtile && (l15 == lh * 4 + r)) e = 0.f;                          \
                den[set * 4 + r] += e;                                              \
            }                                                                       \
        }                                                                           \
    }

    short8 cur[4], nxt[4];
    LOADB(0, cur);
    for (int cb = 0; cb < 16; cb += 2) {
        LOADB(cb + 1, nxt);       // hides under COMPUTE(cur)
        COMPUTE(cur, cb);
        LOADB(cb + 2, cur);       // hides under COMPUTE(nxt); wraps harmlessly at end
        COMPUTE(nxt, cb + 1);
    }
#undef LOADB
#undef COMPUTE

    // reduce over the 16 lanes holding each row's columns (bits 0..3)
#pragma unroll
    for (int p = 0; p < 16; ++p) {
        den[p] += __shfl_xor(den[p], 1);
        den[p] += __shfl_xor(den[p], 2);
        den[p] += __shfl_xor(den[p], 4);
        den[p] += __shfl_xor(den[p], 8);
    }
    if (l15 == 0) {
#pragma unroll
        for (int set = 0; set < 4; ++set)
#pragma unroll
            for (int r = 0; r < 4; ++r)
                den_p[(size_t)chunk * NTOT + row0 + set * 16 + lh * 4 + r] = den[set * 4 + r];
    }
}

// ---------- kernel D: per-row loss, block-reduce, one atomic per block ----------
__global__ __launch_bounds__(256) void final_k(const float* __restrict__ feat,
    const float* __restrict__ labels, const float* __restrict__ den_p,
    const float* __restrict__ h, const float* __restrict__ svec,
    float* __restrict__ out)
{
    __shared__ float hs[10 * DIM];
    __shared__ float svs[10];
    __shared__ float wsum[4];
    const int tid = threadIdx.x;
    for (int i = tid; i < 10 * DIM; i += 256) hs[i] = h[i];
    if (tid < 10) svs[tid] = svec[tid];
    __syncthreads();

    const int wv = tid >> 6, l = tid & 63;
    const int g = l >> 3, j = l & 7;
    const int row = blockIdx.x * 32 + wv * 8 + g;
    const int b = row & (BSZ - 1), v = row >> 12;
    const float4* src = reinterpret_cast<const float4*>(feat + (size_t)(b * 2 + v) * DIM) + j * 4;
    const float4 x0 = src[0], x1 = src[1], x2 = src[2], x3 = src[3];
    float s = x0.x*x0.x + x0.y*x0.y + x0.z*x0.z + x0.w*x0.w
            + x1.x*x1.x + x1.y*x1.y + x1.z*x1.z + x1.w*x1.w
            + x2.x*x2.x + x2.y*x2.y + x2.z*x2.z + x2.w*x2.w
            + x3.x*x3.x + x3.y*x3.y + x3.z*x3.z + x3.w*x3.w;
    s += __shfl_xor(s, 1); s += __shfl_xor(s, 2); s += __shfl_xor(s, 4);
    const float inv = 1.0f / sqrtf(s + 1e-12f);

    const float li = labels[b];
    const float ai = __builtin_amdgcn_exp2f(li * li * C3);
    const float cf[10] = {1.f, 1.f, 0.5f, 1.f/6.f, 1.f/24.f, 1.f/120.f,
                          1.f/720.f, 1.f/5040.f, 1.f/40320.f, 1.f/362880.f};
    float swc = 0.f, sw = 0.f, pm = ai;
    const float* hb = &hs[j * 16];
#pragma unroll
    for (int m = 0; m < 10; ++m) {
        const float* hm = hb + m * DIM;
        const float d = x0.x*hm[0]  + x0.y*hm[1]  + x0.z*hm[2]  + x0.w*hm[3]
                      + x1.x*hm[4]  + x1.y*hm[5]  + x1.z*hm[6]  + x1.w*hm[7]
                      + x2.x*hm[8]  + x2.y*hm[9]  + x2.z*hm[10] + x2.w*hm[11]
                      + x3.x*hm[12] + x3.y*hm[13] + x3.z*hm[14] + x3.w*hm[15];
        const float cpm = cf[m] * pm;
        swc = fmaf(cpm, d, swc);
        sw  = fmaf(cpm, svs[m], sw);
        pm *= li;
    }
    swc += __shfl_xor(swc, 1); swc += __shfl_xor(swc, 2); swc += __shfl_xor(swc, 4);
    swc *= inv;   // f = x * inv

    // den: sum 32 chunk partials; lane j takes chunks 4j..4j+3, then 8-lane reduce
    float dpart = 0.f;
#pragma unroll
    for (int c = 0; c < 4; ++c)
        dpart += den_p[(size_t)(j * 4 + c) * NTOT + row];
    dpart += __shfl_xor(dpart, 1); dpart += __shfl_xor(dpart, 2); dpart += __shfl_xor(dpart, 4);

    const float logd = logf(dpart + 1e-8f);
    const float loss = -(INV_T * swc - (M0 + logd) * sw) / fmaxf(sw, 1e-8f);

    // 8 lanes/row hold identical loss: scale 1/8, wave-sum, LDS-combine, 1 atomic/block
    float part = loss * 0.125f;
    part += __shfl_xor(part, 1);  part += __shfl_xor(part, 2);  part += __shfl_xor(part, 4);
    part += __shfl_xor(part, 8);  part += __shfl_xor(part, 16); part += __shfl_xor(part, 32);
    if (l == 0) wsum[wv] = part;
    __syncthreads();
    if (tid == 0)
        atomicAdd(out, (wsum[0] + wsum[1] + wsum[2] + wsum[3]) * (1.0f / NTOT));
}

extern "C" void kernel_launch(void* const* d_in, const int* in_sizes, int n_in,
                              void* d_out, int out_size, void* d_ws, size_t ws_size,
                              hipStream_t stream) {
    const float* feat   = (const float*)d_in[0];   // (4096, 2, 128) fp32
    const float* labels = (const float*)d_in[1];   // (4096,) fp32

    char* ws = (char*)d_ws;
    unsigned short* F = (unsigned short*)ws;                   // 2 MB bf16 normalized
    float* den_p = (float*)(ws + (size_t)NTOT * DIM * 2);      // 32*8192 f32 = 1 MB
    float* h_p   = den_p + (size_t)NCHUNK * NTOT;              // 256*10*128 f32 = 1.31 MB
    float* sv_p  = h_p + 256 * 10 * DIM;                       // 256*16 f32
    float* h     = sv_p + 256 * 16;                            // 10*128 f32
    float* svec  = h + 10 * DIM;                               // 16 f32
    float* out   = (float*)d_out;

    norm_k<<<256, 256, 0, stream>>>(feat, F, out);
    hsum_p<<<256, 128, 0, stream>>>(F, labels, h_p, sv_p);
    hreduce<<<10, 128, 0, stream>>>(h_p, sv_p, h, svec);
    supcon_mfma<<<1024, 256, 0, stream>>>(F, den_p);
    final_k<<<256, 256, 0, stream>>>(feat, labels, den_p, h, svec, out);
}

// Round 9
// 132.317 us; speedup vs baseline: 1.1772x; 1.1772x over previous
//
#include <hip/hip_runtime.h>
#include <math.h>

#define BSZ 4096
#define NTOT 8192
#define DIM 128
#define NCHUNK 32          // 256-col chunks

typedef __attribute__((ext_vector_type(8))) short short8;   // 8 bf16 = 4 VGPR
typedef __attribute__((ext_vector_type(4))) float float4v;  // MFMA acc

constexpr float INV_T = 1.0f / 0.07f;
constexpr float M0    = INV_T;                 // row max of logits = diag = 1/T
constexpr float LOG2E = 1.4426950408889634f;
constexpr float K1    = INV_T * LOG2E;         // e^(s-M0) = 2^(c*K1 - K1)
constexpr float C3    = -0.5f * LOG2E;         // a = e^(-l^2/2) = 2^(l^2*C3)

__device__ __forceinline__ unsigned short f2bf(float x) {
    union { float f; unsigned u; } u; u.f = x;
    return (unsigned short)((u.u + 0x7FFFu + ((u.u >> 16) & 1)) >> 16);
}
__device__ __forceinline__ float bf2f(unsigned short s) {
    union { unsigned u; float f; } u; u.u = ((unsigned)s) << 16;
    return u.f;
}
__device__ __forceinline__ unsigned pack2(float a, float b) {
    return (unsigned)f2bf(a) | ((unsigned)f2bf(b) << 16);
}

// ---------- kernel A: normalize 32 rows -> F (global + LDS), then h/sv partials ----------
// 256 blocks x 256 thr. Phase 1: 8 lanes/row, 16 floats/lane. Phase 2: t=(d, half).
__global__ __launch_bounds__(256) void norm_hsum_k(const float* __restrict__ feat,
                                                   const float* __restrict__ labels,
                                                   unsigned short* __restrict__ F,
                                                   float* __restrict__ h_p,
                                                   float* __restrict__ sv_p,
                                                   float* __restrict__ out) {
    __shared__ unsigned short Fs[32 * DIM];     // 8 KB: block's normalized rows (bf16)
    __shared__ float hloc[2 * 10 * DIM];        // 10 KB
    __shared__ float svloc[2 * 16];

    if (blockIdx.x == 0 && threadIdx.x == 0) out[0] = 0.f;
    const int tid = threadIdx.x;
    const int wv = tid >> 6, l = tid & 63;
    const int g = l >> 3, j = l & 7;
    const int r  = wv * 8 + g;                  // row in block, 0..31
    const int row = blockIdx.x * 32 + r;
    const int b = row & (BSZ - 1), v = row >> 12;
    const float4* src = reinterpret_cast<const float4*>(feat + (size_t)(b * 2 + v) * DIM) + j * 4;
    const float4 x0 = src[0], x1 = src[1], x2 = src[2], x3 = src[3];
    float s = x0.x*x0.x + x0.y*x0.y + x0.z*x0.z + x0.w*x0.w
            + x1.x*x1.x + x1.y*x1.y + x1.z*x1.z + x1.w*x1.w
            + x2.x*x2.x + x2.y*x2.y + x2.z*x2.z + x2.w*x2.w
            + x3.x*x3.x + x3.y*x3.y + x3.z*x3.z + x3.w*x3.w;
    s += __shfl_xor(s, 1); s += __shfl_xor(s, 2); s += __shfl_xor(s, 4);
    const float inv = 1.0f / sqrtf(s + 1e-12f);
    uint4 w0, w1;
    w0.x = pack2(x0.x*inv, x0.y*inv); w0.y = pack2(x0.z*inv, x0.w*inv);
    w0.z = pack2(x1.x*inv, x1.y*inv); w0.w = pack2(x1.z*inv, x1.w*inv);
    w1.x = pack2(x2.x*inv, x2.y*inv); w1.y = pack2(x2.z*inv, x2.w*inv);
    w1.z = pack2(x3.x*inv, x3.y*inv); w1.w = pack2(x3.z*inv, x3.w*inv);
    uint4* dst = reinterpret_cast<uint4*>(F + (size_t)row * DIM);
    dst[j * 2]     = w0;
    dst[j * 2 + 1] = w1;
    uint4* ldst = reinterpret_cast<uint4*>(Fs + r * DIM);
    ldst[j * 2]     = w0;
    ldst[j * 2 + 1] = w1;
    __syncthreads();

    // phase 2: thread (d, hh) accumulates rows hh*16..hh*16+15 of this block
    const int d = tid & 127, hh = tid >> 7;
    const int k0 = blockIdx.x * 32 + hh * 16;
    float acc[10];
#pragma unroll
    for (int m = 0; m < 10; ++m) acc[m] = 0.f;
    float sv = 0.f;
    for (int kk = 0; kk < 16; ++kk) {
        const int k = k0 + kk;
        const float li = labels[k & (BSZ - 1)];
        const float a = __builtin_amdgcn_exp2f(li * li * C3);
        const float f = bf2f(Fs[(hh * 16 + kk) * DIM + d]);
        float pm = a;
#pragma unroll
        for (int m = 0; m < 10; ++m) {
            acc[m] = fmaf(pm, f, acc[m]);
            if (d == m) sv += pm;
            pm *= li;
        }
    }
#pragma unroll
    for (int m = 0; m < 10; ++m) hloc[hh * (10 * DIM) + m * DIM + d] = acc[m];
    if (d < 10) svloc[hh * 16 + d] = sv;
    __syncthreads();

    float* hp = h_p + (size_t)blockIdx.x * (10 * DIM);
    for (int i = tid; i < 10 * DIM; i += 256) hp[i] = hloc[i] + hloc[10 * DIM + i];
    if (tid < 10) sv_p[blockIdx.x * 16 + tid] = svloc[tid] + svloc[16 + tid];
}

// ---------- kernel B: fold 256 partials -> h[10][128], svec[10] ----------
__global__ __launch_bounds__(256) void hreduce(const float* __restrict__ h_p,
                                               const float* __restrict__ sv_p,
                                               float* __restrict__ h, float* __restrict__ svec) {
    __shared__ float comb[DIM];
    const int m = blockIdx.x;      // 0..9
    const int t = threadIdx.x & 127, half = threadIdx.x >> 7;
    float s = 0.f;
#pragma unroll 4
    for (int b = half * 128; b < half * 128 + 128; ++b)
        s += h_p[(size_t)b * (10 * DIM) + m * DIM + t];
    if (half == 1) comb[t] = s;
    __syncthreads();
    if (half == 0) h[m * DIM + t] = s + comb[t];
    if (m == 0 && threadIdx.x < 10) {
        float vsum = 0.f;
        for (int b = 0; b < 256; ++b) vsum += sv_p[b * 16 + threadIdx.x];
        svec[threadIdx.x] = vsum;
    }
}

// ---------- kernel C: MFMA pairwise sweep, den only, B double-buffer (no spill) ----------
// 64-row stripes, wave owns 64 rows x 256 cols. grid 1024 x 256thr, 3 waves/SIMD cap.
__global__ __launch_bounds__(256, 3) void supcon_mfma(
    const unsigned short* __restrict__ F, float* __restrict__ den_p)
{
    const int tid    = threadIdx.x;
    const int wv     = tid >> 6;
    const int l      = tid & 63;
    const int stripe = blockIdx.x >> 3;        // 0..127
    const int quad   = blockIdx.x & 7;         // 0..7
    const int chunk  = quad * 4 + wv;          // 0..31
    const int row0   = stripe * 64;
    const int colbeg = chunk * 256;
    const int l15 = l & 15, lh = l >> 4;

    // A fragments: row = row0 + set*16 + (l&15), k = kc*32 + (l>>4)*8 + j  (validated r3)
    short8 a[4][4];
#pragma unroll
    for (int set = 0; set < 4; ++set) {
        const unsigned short* rp = F + (size_t)(row0 + set * 16 + l15) * DIM + lh * 8;
#pragma unroll
        for (int kc = 0; kc < 4; ++kc)
            a[set][kc] = *reinterpret_cast<const short8*>(rp + kc * 32);
    }

    float den[16];
#pragma unroll
    for (int p = 0; p < 16; ++p) den[p] = 0.f;

#define LOADB(cb, dst)                                                              \
    {                                                                               \
        const int c0 = (colbeg + (cb) * 16) & (NTOT - 1);                           \
        const unsigned short* cp = F + (size_t)(c0 + l15) * DIM + lh * 8;           \
        dst[0] = *reinterpret_cast<const short8*>(cp);                              \
        dst[1] = *reinterpret_cast<const short8*>(cp + 32);                         \
        dst[2] = *reinterpret_cast<const short8*>(cp + 64);                         \
        dst[3] = *reinterpret_cast<const short8*>(cp + 96);                         \
    }

#define COMPUTE(buf, cb)                                                            \
    {                                                                               \
        const int col0 = colbeg + (cb) * 16;                                        \
        _Pragma("unroll")                                                           \
        for (int set = 0; set < 4; ++set) {                                         \
            float4v acc = {0.f, 0.f, 0.f, 0.f};                                     \
            _Pragma("unroll")                                                       \
            for (int kc = 0; kc < 4; ++kc)                                          \
                acc = __builtin_amdgcn_mfma_f32_16x16x32_bf16(a[set][kc], buf[kc],  \
                                                              acc, 0, 0, 0);       \
            const bool dtile = (col0 == row0 + set * 16);                           \
            _Pragma("unroll")                                                       \
            for (int r = 0; r < 4; ++r) {                                           \
                float e = __builtin_amdgcn_exp2f(__builtin_fmaf(acc[r], K1, -K1));  \
                if (dtile && (l15 == lh * 4 + r)) e = 0.f;                          \
                den[set * 4 + r] += e;                                              \
            }                                                                       \
        }                                                                           \
    }

    short8 cur[4], nxt[4];
    LOADB(0, cur);
    for (int cb = 0; cb < 16; cb += 2) {
        LOADB(cb + 1, nxt);       // hides under COMPUTE(cur)
        COMPUTE(cur, cb);
        LOADB(cb + 2, cur);       // hides under COMPUTE(nxt); wraps harmlessly at end
        COMPUTE(nxt, cb + 1);
    }
#undef LOADB
#undef COMPUTE

    // reduce over the 16 lanes holding each row's columns (bits 0..3)
#pragma unroll
    for (int p = 0; p < 16; ++p) {
        den[p] += __shfl_xor(den[p], 1);
        den[p] += __shfl_xor(den[p], 2);
        den[p] += __shfl_xor(den[p], 4);
        den[p] += __shfl_xor(den[p], 8);
    }
    if (l15 == 0) {
#pragma unroll
        for (int set = 0; set < 4; ++set)
#pragma unroll
            for (int r = 0; r < 4; ++r)
                den_p[(size_t)chunk * NTOT + row0 + set * 16 + lh * 4 + r] = den[set * 4 + r];
    }
}

// ---------- kernel D: per-row loss, block-reduce, one atomic per block ----------
__global__ __launch_bounds__(256) void final_k(const float* __restrict__ feat,
    const float* __restrict__ labels, const float* __restrict__ den_p,
    const float* __restrict__ h, const float* __restrict__ svec,
    float* __restrict__ out)
{
    __shared__ float hs[10 * DIM];
    __shared__ float svs[10];
    __shared__ float wsum[4];
    const int tid = threadIdx.x;
    for (int i = tid; i < 10 * DIM; i += 256) hs[i] = h[i];
    if (tid < 10) svs[tid] = svec[tid];
    __syncthreads();

    const int wv = tid >> 6, l = tid & 63;
    const int g = l >> 3, j = l & 7;
    const int row = blockIdx.x * 32 + wv * 8 + g;
    const int b = row & (BSZ - 1), v = row >> 12;
    const float4* src = reinterpret_cast<const float4*>(feat + (size_t)(b * 2 + v) * DIM) + j * 4;
    const float4 x0 = src[0], x1 = src[1], x2 = src[2], x3 = src[3];
    float s = x0.x*x0.x + x0.y*x0.y + x0.z*x0.z + x0.w*x0.w
            + x1.x*x1.x + x1.y*x1.y + x1.z*x1.z + x1.w*x1.w
            + x2.x*x2.x + x2.y*x2.y + x2.z*x2.z + x2.w*x2.w
            + x3.x*x3.x + x3.y*x3.y + x3.z*x3.z + x3.w*x3.w;
    s += __shfl_xor(s, 1); s += __shfl_xor(s, 2); s += __shfl_xor(s, 4);
    const float inv = 1.0f / sqrtf(s + 1e-12f);

    const float li = labels[b];
    const float ai = __builtin_amdgcn_exp2f(li * li * C3);
    const float cf[10] = {1.f, 1.f, 0.5f, 1.f/6.f, 1.f/24.f, 1.f/120.f,
                          1.f/720.f, 1.f/5040.f, 1.f/40320.f, 1.f/362880.f};
    float swc = 0.f, sw = 0.f, pm = ai;
    const float* hb = &hs[j * 16];
#pragma unroll
    for (int m = 0; m < 10; ++m) {
        const float* hm = hb + m * DIM;
        const float d = x0.x*hm[0]  + x0.y*hm[1]  + x0.z*hm[2]  + x0.w*hm[3]
                      + x1.x*hm[4]  + x1.y*hm[5]  + x1.z*hm[6]  + x1.w*hm[7]
                      + x2.x*hm[8]  + x2.y*hm[9]  + x2.z*hm[10] + x2.w*hm[11]
                      + x3.x*hm[12] + x3.y*hm[13] + x3.z*hm[14] + x3.w*hm[15];
        const float cpm = cf[m] * pm;
        swc = fmaf(cpm, d, swc);
        sw  = fmaf(cpm, svs[m], sw);
        pm *= li;
    }
    swc += __shfl_xor(swc, 1); swc += __shfl_xor(swc, 2); swc += __shfl_xor(swc, 4);
    swc *= inv;   // f = x * inv

    // den: sum 32 chunk partials; lane j takes chunks 4j..4j+3, then 8-lane reduce
    float dpart = 0.f;
#pragma unroll
    for (int c = 0; c < 4; ++c)
        dpart += den_p[(size_t)(j * 4 + c) * NTOT + row];
    dpart += __shfl_xor(dpart, 1); dpart += __shfl_xor(dpart, 2); dpart += __shfl_xor(dpart, 4);

    const float logd = logf(dpart + 1e-8f);
    const float loss = -(INV_T * swc - (M0 + logd) * sw) / fmaxf(sw, 1e-8f);

    // 8 lanes/row hold identical loss: scale 1/8, wave-sum, LDS-combine, 1 atomic/block
    float part = loss * 0.125f;
    part += __shfl_xor(part, 1);  part += __shfl_xor(part, 2);  part += __shfl_xor(part, 4);
    part += __shfl_xor(part, 8);  part += __shfl_xor(part, 16); part += __shfl_xor(part, 32);
    if (l == 0) wsum[wv] = part;
    __syncthreads();
    if (tid == 0)
        atomicAdd(out, (wsum[0] + wsum[1] + wsum[2] + wsum[3]) * (1.0f / NTOT));
}

extern "C" void kernel_launch(void* const* d_in, const int* in_sizes, int n_in,
                              void* d_out, int out_size, void* d_ws, size_t ws_size,
                              hipStream_t stream) {
    const float* feat   = (const float*)d_in[0];   // (4096, 2, 128) fp32
    const float* labels = (const float*)d_in[1];   // (4096,) fp32

    char* ws = (char*)d_ws;
    unsigned short* F = (unsigned short*)ws;                   // 2 MB bf16 normalized
    float* den_p = (float*)(ws + (size_t)NTOT * DIM * 2);      // 32*8192 f32 = 1 MB
    float* h_p   = den_p + (size_t)NCHUNK * NTOT;              // 256*10*128 f32 = 1.31 MB
    float* sv_p  = h_p + 256 * 10 * DIM;                       // 256*16 f32
    float* h     = sv_p + 256 * 16;                            // 10*128 f32
    float* svec  = h + 10 * DIM;                               // 16 f32
    float* out   = (float*)d_out;

    norm_hsum_k<<<256, 256, 0, stream>>>(feat, labels, F, h_p, sv_p, out);
    hreduce<<<10, 256, 0, stream>>>(h_p, sv_p, h, svec);
    supcon_mfma<<<1024, 256, 0, stream>>>(F, den_p);
    final_k<<<256, 256, 0, stream>>>(feat, labels, den_p, h, svec, out);
}

// Round 13
// 96.371 us; speedup vs baseline: 1.6163x; 1.3730x over previous
//
#include <hip/hip_runtime.h>
#include <math.h>

#define BSZ 4096
#define NTOT 8192
#define DIM 128
#define NCHUNK 32          // 256-col chunks

typedef __attribute__((ext_vector_type(8))) short short8;   // 8 bf16 = 4 VGPR
typedef __attribute__((ext_vector_type(4))) float float4v;  // MFMA acc

constexpr float INV_T = 1.0f / 0.07f;
constexpr float M0    = INV_T;                 // row max of logits = diag = 1/T
constexpr float LOG2E = 1.4426950408889634f;
constexpr float K1    = INV_T * LOG2E;         // e^(s-M0) = 2^(c*K1 - K1)
constexpr float C3    = -0.5f * LOG2E;         // a = e^(-l^2/2) = 2^(l^2*C3)

__device__ __forceinline__ unsigned short f2bf(float x) {
    union { float f; unsigned u; } u; u.f = x;
    return (unsigned short)((u.u + 0x7FFFu + ((u.u >> 16) & 1)) >> 16);
}
__device__ __forceinline__ float bf2f(unsigned short s) {
    union { unsigned u; float f; } u; u.u = ((unsigned)s) << 16;
    return u.f;
}
__device__ __forceinline__ unsigned pack2(float a, float b) {
    return (unsigned)f2bf(a) | ((unsigned)f2bf(b) << 16);
}

// ---------- kernel A: normalize 32 rows -> F (global + LDS), then h partials ----------
__global__ __launch_bounds__(256) void norm_hsum_k(const float* __restrict__ feat,
                                                   const float* __restrict__ labels,
                                                   unsigned short* __restrict__ F,
                                                   float* __restrict__ h_p,
                                                   float* __restrict__ out) {
    __shared__ unsigned short Fs[32 * DIM];     // 8 KB
    __shared__ float hloc[2 * 10 * DIM];        // 10 KB

    if (blockIdx.x == 0 && threadIdx.x == 0) out[0] = 0.f;
    const int tid = threadIdx.x;
    const int wv = tid >> 6, l = tid & 63;
    const int g = l >> 3, j = l & 7;
    const int r  = wv * 8 + g;                  // row in block, 0..31
    const int row = blockIdx.x * 32 + r;
    const int b = row & (BSZ - 1), v = row >> 12;
    const float4* src = reinterpret_cast<const float4*>(feat + (size_t)(b * 2 + v) * DIM) + j * 4;
    const float4 x0 = src[0], x1 = src[1], x2 = src[2], x3 = src[3];
    float s = x0.x*x0.x + x0.y*x0.y + x0.z*x0.z + x0.w*x0.w
            + x1.x*x1.x + x1.y*x1.y + x1.z*x1.z + x1.w*x1.w
            + x2.x*x2.x + x2.y*x2.y + x2.z*x2.z + x2.w*x2.w
            + x3.x*x3.x + x3.y*x3.y + x3.z*x3.z + x3.w*x3.w;
    s += __shfl_xor(s, 1); s += __shfl_xor(s, 2); s += __shfl_xor(s, 4);
    const float inv = 1.0f / sqrtf(s + 1e-12f);
    uint4 w0, w1;
    w0.x = pack2(x0.x*inv, x0.y*inv); w0.y = pack2(x0.z*inv, x0.w*inv);
    w0.z = pack2(x1.x*inv, x1.y*inv); w0.w = pack2(x1.z*inv, x1.w*inv);
    w1.x = pack2(x2.x*inv, x2.y*inv); w1.y = pack2(x2.z*inv, x2.w*inv);
    w1.z = pack2(x3.x*inv, x3.y*inv); w1.w = pack2(x3.z*inv, x3.w*inv);
    uint4* dst = reinterpret_cast<uint4*>(F + (size_t)row * DIM);
    dst[j * 2]     = w0;
    dst[j * 2 + 1] = w1;
    uint4* ldst = reinterpret_cast<uint4*>(Fs + r * DIM);
    ldst[j * 2]     = w0;
    ldst[j * 2 + 1] = w1;
    __syncthreads();

    // phase 2: thread (d, hh) accumulates rows hh*16..hh*16+15 of this block
    const int d = tid & 127, hh = tid >> 7;
    const int k0 = blockIdx.x * 32 + hh * 16;
    float acc[10];
#pragma unroll
    for (int m = 0; m < 10; ++m) acc[m] = 0.f;
    for (int kk = 0; kk < 16; ++kk) {
        const int k = k0 + kk;
        const float li = labels[k & (BSZ - 1)];
        const float a = __builtin_amdgcn_exp2f(li * li * C3);
        const float f = bf2f(Fs[(hh * 16 + kk) * DIM + d]);
        float pm = a;
#pragma unroll
        for (int m = 0; m < 10; ++m) {
            acc[m] = fmaf(pm, f, acc[m]);
            pm *= li;
        }
    }
#pragma unroll
    for (int m = 0; m < 10; ++m) hloc[hh * (10 * DIM) + m * DIM + d] = acc[m];
    __syncthreads();

    float* hp = h_p + (size_t)blockIdx.x * (10 * DIM);
    for (int i = tid; i < 10 * DIM; i += 256) hp[i] = hloc[i] + hloc[10 * DIM + i];
}

// ---------- kernel B: fold 256 partials -> h[10][128]; block 10 computes svec ----------
__global__ __launch_bounds__(1024) void hreduce(const float* __restrict__ h_p,
                                                const float* __restrict__ labels,
                                                float* __restrict__ h,
                                                float* __restrict__ svec) {
    const int m = blockIdx.x;
    const int t = threadIdx.x;
    if (m < 10) {
        __shared__ float red[8][DIM];
        const int d = t & 127, bb = t >> 7;
        float s = 0.f;
#pragma unroll 4
        for (int k = 0; k < 32; ++k)
            s += h_p[(size_t)(bb * 32 + k) * (10 * DIM) + m * DIM + d];
        red[bb][d] = s;
        __syncthreads();
        if (bb == 0) {
            float rr = 0.f;
#pragma unroll
            for (int x = 0; x < 8; ++x) rr += red[x][d];
            h[m * DIM + d] = rr;
        }
    } else {
        __shared__ float sred[16][10];
        float part[10];
#pragma unroll
        for (int mm = 0; mm < 10; ++mm) part[mm] = 0.f;
        for (int k = t; k < NTOT; k += 1024) {
            const float li = labels[k & (BSZ - 1)];
            float pm = __builtin_amdgcn_exp2f(li * li * C3);
#pragma unroll
            for (int mm = 0; mm < 10; ++mm) { part[mm] += pm; pm *= li; }
        }
#pragma unroll
        for (int mm = 0; mm < 10; ++mm) {
#pragma unroll
            for (int off = 32; off >= 1; off >>= 1) part[mm] += __shfl_xor(part[mm], off);
        }
        const int wid = t >> 6;
        if ((t & 63) == 0) {
#pragma unroll
            for (int mm = 0; mm < 10; ++mm) sred[wid][mm] = part[mm];
        }
        __syncthreads();
        if (t < 10) {
            float v = 0.f;
#pragma unroll
            for (int x = 0; x < 16; ++x) v += sred[x][t];
            svec[t] = v;
        }
    }
}

// ---------- kernel C: block-cooperative MFMA sweep, LDS-staged B via global_load_lds ----------
// Block = 256 rows x 256 cols, 4 waves split rows. B staged in 4 stages of 64 cols,
// double-buffered 2x16KB. LDS layout per stage: [colblk16][kslot][col] cells of 16B,
// exactly linear in (q*256 + tid) so DMA lane order matches.
__global__ __launch_bounds__(256) void supcon_mfma(
    const unsigned short* __restrict__ F, float* __restrict__ den_p)
{
    __shared__ __align__(16) unsigned short Bs[2][64 * DIM];   // 2 x 16 KB

    const int tid = threadIdx.x;
    const int wv  = tid >> 6, l = tid & 63;
    const int l15 = l & 15, lh = l >> 4;
    const int rs  = blockIdx.x >> 5;          // 0..31 row-stripe
    const int cs  = blockIdx.x & 31;          // 0..31 col-chunk
    const int row0 = rs * 256 + wv * 64;      // this wave's 64 rows
    const int c0   = cs * 256;
    const int ks   = wv * 4 + lh;             // kslot this lane writes in DMA

#define ISSUE_STAGE(sidx, buf)                                                          \
    {                                                                                   \
        _Pragma("unroll")                                                               \
        for (int q = 0; q < 4; ++q) {                                                   \
            const unsigned short* gsrc =                                                \
                F + (size_t)(c0 + (sidx) * 64 + q * 16 + l15) * DIM + ks * 8;           \
            unsigned short* ldst = &Bs[buf][(q * 256 + wv * 64) * 8];                   \
            __builtin_amdgcn_global_load_lds(                                           \
                (const __attribute__((address_space(1))) unsigned int*)gsrc,            \
                (__attribute__((address_space(3))) unsigned int*)ldst, 16, 0, 0);       \
        }                                                                               \
    }

    ISSUE_STAGE(0, 0);

    // A fragments: row = row0 + set*16 + l15, k = kc*32 + lh*8 + j (validated r3)
    short8 a[4][4];
#pragma unroll
    for (int set = 0; set < 4; ++set) {
        const unsigned short* rp = F + (size_t)(row0 + set * 16 + l15) * DIM + lh * 8;
#pragma unroll
        for (int kc = 0; kc < 4; ++kc)
            a[set][kc] = *reinterpret_cast<const short8*>(rp + kc * 32);
    }

    float den[16];
#pragma unroll
    for (int p = 0; p < 16; ++p) den[p] = 0.f;

    for (int s = 0; s < 4; ++s) {
        __syncthreads();                       // drains this wave's DMA(s) (+A on s=0); all waves synced
        if (s < 3) ISSUE_STAGE(s + 1, (s + 1) & 1);   // flies under compute below

        const unsigned short* bs = Bs[s & 1];
#pragma unroll
        for (int sb = 0; sb < 4; ++sb) {
            short8 bfr[4];
#pragma unroll
            for (int kc = 0; kc < 4; ++kc)
                bfr[kc] = *reinterpret_cast<const short8*>(
                    bs + sb * 2048 + (kc * 4 + lh) * 128 + l15 * 8);
            const int col0g = c0 + s * 64 + sb * 16;
#pragma unroll
            for (int set = 0; set < 4; ++set) {
                float4v acc = {0.f, 0.f, 0.f, 0.f};
#pragma unroll
                for (int kc = 0; kc < 4; ++kc)
                    acc = __builtin_amdgcn_mfma_f32_16x16x32_bf16(a[set][kc], bfr[kc], acc, 0, 0, 0);
                const bool dtile = (col0g == row0 + set * 16);   // wave-uniform
#pragma unroll
                for (int r = 0; r < 4; ++r) {
                    float e = __builtin_amdgcn_exp2f(__builtin_fmaf(acc[r], K1, -K1));
                    if (dtile && (l15 == lh * 4 + r)) e = 0.f;   // i == k
                    den[set * 4 + r] += e;
                }
            }
        }
    }
#undef ISSUE_STAGE

    // reduce over the 16 lanes holding each row's columns
#pragma unroll
    for (int p = 0; p < 16; ++p) {
        den[p] += __shfl_xor(den[p], 1);
        den[p] += __shfl_xor(den[p], 2);
        den[p] += __shfl_xor(den[p], 4);
        den[p] += __shfl_xor(den[p], 8);
    }
    if (l15 == 0) {
#pragma unroll
        for (int set = 0; set < 4; ++set)
#pragma unroll
            for (int r = 0; r < 4; ++r)
                den_p[(size_t)cs * NTOT + row0 + set * 16 + lh * 4 + r] = den[set * 4 + r];
    }
}

// ---------- kernel D: per-row loss, block-reduce, one atomic per block ----------
__global__ __launch_bounds__(256) void final_k(const float* __restrict__ feat,
    const float* __restrict__ labels, const float* __restrict__ den_p,
    const float* __restrict__ h, const float* __restrict__ svec,
    float* __restrict__ out)
{
    __shared__ float hs[10 * DIM];
    __shared__ float svs[10];
    __shared__ float wsum[4];
    const int tid = threadIdx.x;
    for (int i = tid; i < 10 * DIM; i += 256) hs[i] = h[i];
    if (tid < 10) svs[tid] = svec[tid];
    __syncthreads();

    const int wv = tid >> 6, l = tid & 63;
    const int g = l >> 3, j = l & 7;
    const int row = blockIdx.x * 32 + wv * 8 + g;
    const int b = row & (BSZ - 1), v = row >> 12;
    const float4* src = reinterpret_cast<const float4*>(feat + (size_t)(b * 2 + v) * DIM) + j * 4;
    const float4 x0 = src[0], x1 = src[1], x2 = src[2], x3 = src[3];
    float s = x0.x*x0.x + x0.y*x0.y + x0.z*x0.z + x0.w*x0.w
            + x1.x*x1.x + x1.y*x1.y + x1.z*x1.z + x1.w*x1.w
            + x2.x*x2.x + x2.y*x2.y + x2.z*x2.z + x2.w*x2.w
            + x3.x*x3.x + x3.y*x3.y + x3.z*x3.z + x3.w*x3.w;
    s += __shfl_xor(s, 1); s += __shfl_xor(s, 2); s += __shfl_xor(s, 4);
    const float inv = 1.0f / sqrtf(s + 1e-12f);

    const float li = labels[b];
    const float ai = __builtin_amdgcn_exp2f(li * li * C3);
    const float cf[10] = {1.f, 1.f, 0.5f, 1.f/6.f, 1.f/24.f, 1.f/120.f,
                          1.f/720.f, 1.f/5040.f, 1.f/40320.f, 1.f/362880.f};
    float swc = 0.f, sw = 0.f, pm = ai;
    const float* hb = &hs[j * 16];
#pragma unroll
    for (int m = 0; m < 10; ++m) {
        const float* hm = hb + m * DIM;
        const float d = x0.x*hm[0]  + x0.y*hm[1]  + x0.z*hm[2]  + x0.w*hm[3]
                      + x1.x*hm[4]  + x1.y*hm[5]  + x1.z*hm[6]  + x1.w*hm[7]
                      + x2.x*hm[8]  + x2.y*hm[9]  + x2.z*hm[10] + x2.w*hm[11]
                      + x3.x*hm[12] + x3.y*hm[13] + x3.z*hm[14] + x3.w*hm[15];
        const float cpm = cf[m] * pm;
        swc = fmaf(cpm, d, swc);
        sw  = fmaf(cpm, svs[m], sw);
        pm *= li;
    }
    swc += __shfl_xor(swc, 1); swc += __shfl_xor(swc, 2); swc += __shfl_xor(swc, 4);
    swc *= inv;   // f = x * inv

    // den: sum 32 chunk partials; lane j takes chunks 4j..4j+3, then 8-lane reduce
    float dpart = 0.f;
#pragma unroll
    for (int c = 0; c < 4; ++c)
        dpart += den_p[(size_t)(j * 4 + c) * NTOT + row];
    dpart += __shfl_xor(dpart, 1); dpart += __shfl_xor(dpart, 2); dpart += __shfl_xor(dpart, 4);

    const float logd = logf(dpart + 1e-8f);
    const float loss = -(INV_T * swc - (M0 + logd) * sw) / fmaxf(sw, 1e-8f);

    // 8 lanes/row hold identical loss: scale 1/8, wave-sum, LDS-combine, 1 atomic/block
    float part = loss * 0.125f;
    part += __shfl_xor(part, 1);  part += __shfl_xor(part, 2);  part += __shfl_xor(part, 4);
    part += __shfl_xor(part, 8);  part += __shfl_xor(part, 16); part += __shfl_xor(part, 32);
    if (l == 0) wsum[wv] = part;
    __syncthreads();
    if (tid == 0)
        atomicAdd(out, (wsum[0] + wsum[1] + wsum[2] + wsum[3]) * (1.0f / NTOT));
}

extern "C" void kernel_launch(void* const* d_in, const int* in_sizes, int n_in,
                              void* d_out, int out_size, void* d_ws, size_t ws_size,
                              hipStream_t stream) {
    const float* feat   = (const float*)d_in[0];   // (4096, 2, 128) fp32
    const float* labels = (const float*)d_in[1];   // (4096,) fp32

    char* ws = (char*)d_ws;
    unsigned short* F = (unsigned short*)ws;                   // 2 MB bf16 normalized
    float* den_p = (float*)(ws + (size_t)NTOT * DIM * 2);      // 32*8192 f32 = 1 MB
    float* h_p   = den_p + (size_t)NCHUNK * NTOT;              // 256*10*128 f32 = 1.31 MB
    float* h     = h_p + 256 * 10 * DIM;                       // 10*128 f32
    float* svec  = h + 10 * DIM;                               // 16 f32
    float* out   = (float*)d_out;

    norm_hsum_k<<<256, 256, 0, stream>>>(feat, labels, F, h_p, out);
    hreduce<<<11, 1024, 0, stream>>>(h_p, labels, h, svec);
    supcon_mfma<<<1024, 256, 0, stream>>>(F, den_p);
    final_k<<<256, 256, 0, stream>>>(feat, labels, den_p, h, svec, out);
}